// Round 1
// baseline (24536.035 us; speedup 1.0000x reference)
//
#include <hip/hip_runtime.h>
#include <math.h>

#define RB  16    // rows per block
#define DIN 192
#define HD  256

// ---------------------------------------------------------------------------
// Kernel A: fused fourier + concat + LN1 + TB1 + LN2 + TB2 + scores
// One block = 16 rows. 256 threads (4 waves).
//  Phase 0: wave-per-row feature build + LayerNorm (shfl reduce over 64 lanes)
//  Phases 1-2: TB1 matmuls, thread t owns output column j=t, rows in registers
//  Phase 3: LN2 wave-per-row
//  Phases 4a-4b: TB2 matmuls + residual
//  Phase 5: scores (256->4) -> global scores buffer
// ---------------------------------------------------------------------------
__global__ __launch_bounds__(256, 2)
void iab_rows_kernel(
    const float* __restrict__ v, const float* __restrict__ af,
    const float* __restrict__ fw, const float* __restrict__ fb,
    const float* __restrict__ ln1g, const float* __restrict__ ln1b,
    const float* __restrict__ w_sw1, const float* __restrict__ w_ss1,
    const float* __restrict__ w_sig1, const float* __restrict__ b_sig1,
    const float* __restrict__ w_sc1,
    const float* __restrict__ ln2g, const float* __restrict__ ln2b,
    const float* __restrict__ w_sw2, const float* __restrict__ w_ss2,
    const float* __restrict__ w_sig2, const float* __restrict__ b_sig2,
    const float* __restrict__ w_sc2,
    const float* __restrict__ outw, const float* __restrict__ outb,
    float* __restrict__ scores, int N)
{
  __shared__ float sX [RB][DIN];  // xhat1 (after LN1)
  __shared__ float sB [RB][HD];   // b = silu(h_sw)*h_ss  (TB1 then TB2)
  __shared__ float sX2[RB][HD];   // x2 = TB1 out, later x_final
  __shared__ float sL [RB][HD];   // xhat2 (after LN2)

  const int t    = threadIdx.x;
  const int wave = t >> 6;
  const int lane = t & 63;
  const int row0 = blockIdx.x * RB;

  // ---- Phase 0: features + LN1 (wave handles 4 rows) ----
  for (int rr = 0; rr < RB / 4; ++rr) {
    const int r = wave * (RB / 4) + rr;
    const int g = row0 + r;
    float e0 = 0.f, e1 = 0.f, e2 = 0.f;
    if (g < N) {
      const float vx = v[3 * (size_t)g + 0];
      const float vy = v[3 * (size_t)g + 1];
      const float vz = v[3 * (size_t)g + 2];
      const float nrm = sqrtf(vx * vx + vy * vy + vz * vz);
      e0 = cosf(6.283185307179586f * (nrm * fw[lane] + fb[lane]));
      const float* a = af + (size_t)g * 128;
      e1 = a[lane];
      e2 = a[lane + 64];
    }
    float s  = e0 + e1 + e2;
    float sq = e0 * e0 + e1 * e1 + e2 * e2;
    #pragma unroll
    for (int o = 32; o >= 1; o >>= 1) {
      s  += __shfl_xor(s,  o);
      sq += __shfl_xor(sq, o);
    }
    const float mean = s * (1.f / 192.f);
    const float var  = fmaxf(sq * (1.f / 192.f) - mean * mean, 0.f);
    const float rstd = rsqrtf(var + 1e-5f);
    sX[r][lane]       = (e0 - mean) * rstd * ln1g[lane]       + ln1b[lane];
    sX[r][lane + 64]  = (e1 - mean) * rstd * ln1g[lane + 64]  + ln1b[lane + 64];
    sX[r][lane + 128] = (e2 - mean) * rstd * ln1g[lane + 128] + ln1b[lane + 128];
  }
  __syncthreads();

  // ---- Phase 1: TB1 h_sw, h_ss -> b = silu(h_sw) * h_ss ----
  {
    float asw[RB], ass[RB];
    #pragma unroll
    for (int r = 0; r < RB; ++r) { asw[r] = 0.f; ass[r] = 0.f; }
    const float* Wa = w_sw1 + (size_t)t * DIN;
    const float* Wb = w_ss1 + (size_t)t * DIN;
    for (int k = 0; k < DIN; k += 4) {
      const float4 a4 = *(const float4*)(Wa + k);
      const float4 b4 = *(const float4*)(Wb + k);
      #pragma unroll
      for (int r = 0; r < RB; ++r) {
        const float4 x4 = *(const float4*)(&sX[r][k]);
        asw[r] += x4.x * a4.x + x4.y * a4.y + x4.z * a4.z + x4.w * a4.w;
        ass[r] += x4.x * b4.x + x4.y * b4.y + x4.z * b4.z + x4.w * b4.w;
      }
    }
    #pragma unroll
    for (int r = 0; r < RB; ++r) {
      const float u = asw[r];
      const float sig = 1.f / (1.f + expf(-u));
      sB[r][t] = u * sig * ass[r];
    }
  }
  __syncthreads();

  // ---- Phase 2: TB1 h_sig, b @ w_scale.T -> x2 ----
  {
    float asig[RB], absc[RB];
    #pragma unroll
    for (int r = 0; r < RB; ++r) { asig[r] = 0.f; absc[r] = 0.f; }
    const float* Wg = w_sig1 + (size_t)t * DIN;
    for (int k = 0; k < DIN; k += 4) {
      const float4 g4 = *(const float4*)(Wg + k);
      #pragma unroll
      for (int r = 0; r < RB; ++r) {
        const float4 x4 = *(const float4*)(&sX[r][k]);
        asig[r] += x4.x * g4.x + x4.y * g4.y + x4.z * g4.z + x4.w * g4.w;
      }
    }
    const float* Ws = w_sc1 + (size_t)t * HD;
    for (int k = 0; k < HD; k += 4) {
      const float4 s4 = *(const float4*)(Ws + k);
      #pragma unroll
      for (int r = 0; r < RB; ++r) {
        const float4 b4 = *(const float4*)(&sB[r][k]);
        absc[r] += b4.x * s4.x + b4.y * s4.y + b4.z * s4.z + b4.w * s4.w;
      }
    }
    const float bias = b_sig1[t];
    #pragma unroll
    for (int r = 0; r < RB; ++r) {
      const float sig = 1.f / (1.f + expf(-(asig[r] + bias)));
      sX2[r][t] = sig * absc[r];   // no residual in TB1
    }
  }
  __syncthreads();

  // ---- Phase 3: LN2 over x2 (wave-per-row, 4 elems/lane) ----
  for (int rr = 0; rr < RB / 4; ++rr) {
    const int r = wave * (RB / 4) + rr;
    float e[4];
    #pragma unroll
    for (int i = 0; i < 4; ++i) e[i] = sX2[r][lane + 64 * i];
    float s  = e[0] + e[1] + e[2] + e[3];
    float sq = e[0]*e[0] + e[1]*e[1] + e[2]*e[2] + e[3]*e[3];
    #pragma unroll
    for (int o = 32; o >= 1; o >>= 1) {
      s  += __shfl_xor(s,  o);
      sq += __shfl_xor(sq, o);
    }
    const float mean = s * (1.f / 256.f);
    const float var  = fmaxf(sq * (1.f / 256.f) - mean * mean, 0.f);
    const float rstd = rsqrtf(var + 1e-5f);
    #pragma unroll
    for (int i = 0; i < 4; ++i) {
      const int k = lane + 64 * i;
      sL[r][k] = (e[i] - mean) * rstd * ln2g[k] + ln2b[k];
    }
  }
  __syncthreads();

  // ---- Phase 4a: TB2 h_sw, h_ss -> b2 ----
  {
    float asw[RB], ass[RB];
    #pragma unroll
    for (int r = 0; r < RB; ++r) { asw[r] = 0.f; ass[r] = 0.f; }
    const float* Wa = w_sw2 + (size_t)t * HD;
    const float* Wb = w_ss2 + (size_t)t * HD;
    for (int k = 0; k < HD; k += 4) {
      const float4 a4 = *(const float4*)(Wa + k);
      const float4 b4 = *(const float4*)(Wb + k);
      #pragma unroll
      for (int r = 0; r < RB; ++r) {
        const float4 x4 = *(const float4*)(&sL[r][k]);
        asw[r] += x4.x * a4.x + x4.y * a4.y + x4.z * a4.z + x4.w * a4.w;
        ass[r] += x4.x * b4.x + x4.y * b4.y + x4.z * b4.z + x4.w * b4.w;
      }
    }
    #pragma unroll
    for (int r = 0; r < RB; ++r) {
      const float u = asw[r];
      const float sig = 1.f / (1.f + expf(-u));
      sB[r][t] = u * sig * ass[r];
    }
  }
  __syncthreads();

  // ---- Phase 4b: TB2 h_sig, b2 @ w_scale.T -> x_final = x2 + y ----
  {
    float asig[RB], absc[RB];
    #pragma unroll
    for (int r = 0; r < RB; ++r) { asig[r] = 0.f; absc[r] = 0.f; }
    const float* Wg = w_sig2 + (size_t)t * HD;
    for (int k = 0; k < HD; k += 4) {
      const float4 g4 = *(const float4*)(Wg + k);
      #pragma unroll
      for (int r = 0; r < RB; ++r) {
        const float4 x4 = *(const float4*)(&sL[r][k]);
        asig[r] += x4.x * g4.x + x4.y * g4.y + x4.z * g4.z + x4.w * g4.w;
      }
    }
    const float* Ws = w_sc2 + (size_t)t * HD;
    for (int k = 0; k < HD; k += 4) {
      const float4 s4 = *(const float4*)(Ws + k);
      #pragma unroll
      for (int r = 0; r < RB; ++r) {
        const float4 b4 = *(const float4*)(&sB[r][k]);
        absc[r] += b4.x * s4.x + b4.y * s4.y + b4.z * s4.z + b4.w * s4.w;
      }
    }
    const float bias = b_sig2[t];
    #pragma unroll
    for (int r = 0; r < RB; ++r) {
      const float sig = 1.f / (1.f + expf(-(asig[r] + bias)));
      sX2[r][t] = sX2[r][t] + sig * absc[r];   // residual
    }
  }
  __syncthreads();

  // ---- Phase 5: scores = x_final @ out_w.T + out_b  (64 (row,head) pairs) ----
  if (t < RB * 4) {
    const int r = t >> 2;
    const int h = t & 3;
    const int g = row0 + r;
    if (g < N) {
      float acc = outb[h];
      const float* W = outw + (size_t)h * HD;
      for (int k = 0; k < HD; k += 4) {
        const float4 x4 = *(const float4*)(&sX2[r][k]);
        const float4 w4 = *(const float4*)(W + k);
        acc += x4.x * w4.x + x4.y * w4.y + x4.z * w4.z + x4.w * w4.w;
      }
      scores[(size_t)g * 4 + h] = acc;
    }
  }
}

// ---------------------------------------------------------------------------
// Kernel B: segment softmax + weighted 3-vector pooling.
// edge_group_idx is SORTED, so each segment is a contiguous row range found
// by binary search. One wave per segment; lane = (row_in_chunk, head).
// Deterministic (no atomics); empty segments -> zeros (matches reference).
// ---------------------------------------------------------------------------
__device__ __forceinline__ int iab_lower_bound(const int* __restrict__ a, int n, int key)
{
  int lo = 0, hi = n;
  while (lo < hi) {
    const int mid = (lo + hi) >> 1;
    if (a[mid] < key) lo = mid + 1; else hi = mid;
  }
  return lo;
}

__global__ __launch_bounds__(256)
void iab_segpool_kernel(const float* __restrict__ scores,
                        const float* __restrict__ v,
                        const int* __restrict__ gidx,
                        float* __restrict__ out, int N, int E)
{
  const int seg  = blockIdx.x * 4 + (threadIdx.x >> 6);
  const int lane = threadIdx.x & 63;
  if (seg >= E) return;

  const int lo = iab_lower_bound(gidx, N, seg);
  const int hi = iab_lower_bound(gidx, N, seg + 1);

  const int h  = lane & 3;
  const int ro = lane >> 2;   // 0..15 rows per chunk

  // pass 1: per-head max
  float m = -INFINITY;
  for (int base = lo; base < hi; base += 16) {
    const int r = base + ro;
    if (r < hi) m = fmaxf(m, scores[(size_t)r * 4 + h]);
  }
  #pragma unroll
  for (int o = 4; o < 64; o <<= 1) m = fmaxf(m, __shfl_xor(m, o));

  // pass 2: sum of exp and weighted v accumulation
  float ssum = 0.f, w0 = 0.f, w1 = 0.f, w2 = 0.f;
  for (int base = lo; base < hi; base += 16) {
    const int r = base + ro;
    if (r < hi) {
      const float e = expf(scores[(size_t)r * 4 + h] - m);
      ssum += e;
      w0 += e * v[3 * (size_t)r + 0];
      w1 += e * v[3 * (size_t)r + 1];
      w2 += e * v[3 * (size_t)r + 2];
    }
  }
  #pragma unroll
  for (int o = 4; o < 64; o <<= 1) {
    ssum += __shfl_xor(ssum, o);
    w0   += __shfl_xor(w0, o);
    w1   += __shfl_xor(w1, o);
    w2   += __shfl_xor(w2, o);
  }

  if (ro == 0) {
    const float inv = (hi > lo) ? (1.f / ssum) : 0.f;
    out[(size_t)seg * 12 + h * 3 + 0] = w0 * inv;
    out[(size_t)seg * 12 + h * 3 + 1] = w1 * inv;
    out[(size_t)seg * 12 + h * 3 + 2] = w2 * inv;
  }
}

// ---------------------------------------------------------------------------
extern "C" void kernel_launch(void* const* d_in, const int* in_sizes, int n_in,
                              void* d_out, int out_size, void* d_ws, size_t ws_size,
                              hipStream_t stream)
{
  const float* v     = (const float*)d_in[0];
  const float* af    = (const float*)d_in[1];
  const int*   gidx  = (const int*)  d_in[2];
  // d_in[3] = num_edges (device scalar, unused; E derived from out_size)
  const float* fw    = (const float*)d_in[4];
  const float* fb    = (const float*)d_in[5];
  const float* ln1g  = (const float*)d_in[6];
  const float* ln1b  = (const float*)d_in[7];
  const float* wsw1  = (const float*)d_in[8];
  const float* wss1  = (const float*)d_in[9];
  const float* wsig1 = (const float*)d_in[10];
  const float* bsig1 = (const float*)d_in[11];
  const float* wsc1  = (const float*)d_in[12];
  const float* ln2g  = (const float*)d_in[13];
  const float* ln2b  = (const float*)d_in[14];
  const float* wsw2  = (const float*)d_in[15];
  const float* wss2  = (const float*)d_in[16];
  const float* wsig2 = (const float*)d_in[17];
  const float* bsig2 = (const float*)d_in[18];
  const float* wsc2  = (const float*)d_in[19];
  const float* outw  = (const float*)d_in[20];
  const float* outb  = (const float*)d_in[21];

  const int N = in_sizes[0] / 3;
  const int E = out_size / 12;

  float* scores = (float*)d_ws;   // N*4 floats = 16 MB

  dim3 blk(256);
  dim3 grdA((N + RB - 1) / RB);
  hipLaunchKernelGGL(iab_rows_kernel, grdA, blk, 0, stream,
                     v, af, fw, fb, ln1g, ln1b,
                     wsw1, wss1, wsig1, bsig1, wsc1,
                     ln2g, ln2b, wsw2, wss2, wsig2, bsig2, wsc2,
                     outw, outb, scores, N);

  dim3 grdB((E + 3) / 4);
  hipLaunchKernelGGL(iab_segpool_kernel, grdB, blk, 0, stream,
                     scores, v, gidx, (float*)d_out, N, E);
}

// Round 2
// 5447.650 us; speedup vs baseline: 4.5040x; 4.5040x over previous
//
#include <hip/hip_runtime.h>
#include <hip/hip_bf16.h>
#include <math.h>

#define DIN  192
#define HD   256
#define ROWS 32      // rows per block
#define STR  264     // padded LDS row stride in bf16 elems (528B = 33*16B)

typedef __bf16 bf16v;
typedef bf16v bf16x8 __attribute__((ext_vector_type(8)));
typedef float f32x4  __attribute__((ext_vector_type(4)));

static __device__ __forceinline__ f32x4 mfma16(bf16x8 a, bf16x8 b, f32x4 c) {
  return __builtin_amdgcn_mfma_f32_16x16x32_bf16(a, b, c, 0, 0, 0);
}

// bf16 weight region layout (elements) inside d_ws after the scores buffer
#define OFF_WSW1 0
#define OFF_WSS1 49152
#define OFF_WSG1 98304
#define OFF_WSC1 147456
#define OFF_WSW2 212992
#define OFF_WSS2 278528
#define OFF_WSG2 344064
#define OFF_WSC2 409600
#define OFF_WOUT 475136
#define W_TOTAL  476160

// ---------------------------------------------------------------------------
// Weight fp32 -> bf16 conversion (runs every launch; ~1 MB, trivial)
// ---------------------------------------------------------------------------
__global__ void iab_wconv_kernel(const float* __restrict__ a0, const float* __restrict__ a1,
                                 const float* __restrict__ a2, const float* __restrict__ a3,
                                 const float* __restrict__ a4, const float* __restrict__ a5,
                                 const float* __restrict__ a6, const float* __restrict__ a7,
                                 const float* __restrict__ a8, __hip_bfloat16* __restrict__ out)
{
  const int i = blockIdx.x * 256 + threadIdx.x;
  if (i >= W_TOTAL) return;
  const float* src; int off;
  if      (i < OFF_WSS1) { src = a0; off = OFF_WSW1; }
  else if (i < OFF_WSG1) { src = a1; off = OFF_WSS1; }
  else if (i < OFF_WSC1) { src = a2; off = OFF_WSG1; }
  else if (i < OFF_WSW2) { src = a3; off = OFF_WSC1; }
  else if (i < OFF_WSS2) { src = a4; off = OFF_WSW2; }
  else if (i < OFF_WSG2) { src = a5; off = OFF_WSS2; }
  else if (i < OFF_WSC2) { src = a6; off = OFF_WSG2; }
  else if (i < OFF_WOUT) { src = a7; off = OFF_WSC2; }
  else                   { src = a8; off = OFF_WOUT; }
  out[i] = __float2bfloat16(src[i - off]);
}

// ---------------------------------------------------------------------------
// Main fused kernel: features+LN1 -> TB1 -> LN2 -> TB2 -> scores, MFMA path.
// 32 rows/block, 256 threads (4 waves). Wave w owns output cols [64w,64w+64)
// for ALL 32 rows (2 M-tiles of 16). 16x16x32 bf16 MFMA.
// C-layout (verified): col = lane&15, row = 4*(lane>>4) + reg.
// A-frag: row = lane&15, k = 32*s + 8*(lane>>4) + j (16B contiguous).
// B-frag: col = lane&15, same k mapping (mirrored -> exact for any HW perm).
// ---------------------------------------------------------------------------
__global__ __launch_bounds__(256, 3)
void iab_rows_mfma(
    const float* __restrict__ v, const float* __restrict__ af,
    const float* __restrict__ fw, const float* __restrict__ fb,
    const float* __restrict__ ln1g, const float* __restrict__ ln1b,
    const float* __restrict__ bsig1,
    const float* __restrict__ ln2g, const float* __restrict__ ln2b,
    const float* __restrict__ bsig2,
    const float* __restrict__ outb,
    const __hip_bfloat16* __restrict__ wc,
    float* __restrict__ scores, int N)
{
  __shared__ __align__(16) __hip_bfloat16 bufA [ROWS][STR];  // xhat1 then xhat2
  __shared__ __align__(16) __hip_bfloat16 bufB [ROWS][STR];  // b1 then b2
  __shared__ __align__(16) __hip_bfloat16 bufX2[ROWS][STR];  // sigma1 -> x2 -> xf

  const __hip_bfloat16* Wsw1 = wc + OFF_WSW1;
  const __hip_bfloat16* Wss1 = wc + OFF_WSS1;
  const __hip_bfloat16* Wsg1 = wc + OFF_WSG1;
  const __hip_bfloat16* Wsc1 = wc + OFF_WSC1;
  const __hip_bfloat16* Wsw2 = wc + OFF_WSW2;
  const __hip_bfloat16* Wss2 = wc + OFF_WSS2;
  const __hip_bfloat16* Wsg2 = wc + OFF_WSG2;
  const __hip_bfloat16* Wsc2 = wc + OFF_WSC2;
  const __hip_bfloat16* Wout = wc + OFF_WOUT;

  const int t    = threadIdx.x;
  const int wave = t >> 6;
  const int lane = t & 63;
  const int row0 = blockIdx.x * ROWS;
  const int cc   = lane & 15;     // col within 16-tile / A-row within tile
  const int g4   = lane >> 4;     // 0..3 lane group
  const int kb   = g4 * 8;        // k offset of this lane's 8 contiguous elems

  // ---- Phase 0: features + LN1 -> bufA (bf16). 8 rows per wave. ----
  {
    const float fwl = fw[lane], fbl = fb[lane];
    const float g1a = ln1g[lane], g1b = ln1g[lane + 64], g1c = ln1g[lane + 128];
    const float o1a = ln1b[lane], o1b = ln1b[lane + 64], o1c = ln1b[lane + 128];
    for (int rr = 0; rr < 8; ++rr) {
      const int r = wave * 8 + rr;
      const int g = row0 + r;
      float e0 = 0.f, e1 = 0.f, e2 = 0.f;
      if (g < N) {
        const float vx = v[3 * (size_t)g + 0];
        const float vy = v[3 * (size_t)g + 1];
        const float vz = v[3 * (size_t)g + 2];
        const float nrm = sqrtf(vx * vx + vy * vy + vz * vz);
        e0 = cosf(6.283185307179586f * (nrm * fwl + fbl));
        const float* a = af + (size_t)g * 128;
        e1 = a[lane];
        e2 = a[lane + 64];
      }
      float s  = e0 + e1 + e2;
      float sq = e0 * e0 + e1 * e1 + e2 * e2;
      #pragma unroll
      for (int o = 32; o >= 1; o >>= 1) {
        s  += __shfl_xor(s,  o);
        sq += __shfl_xor(sq, o);
      }
      const float mean = s * (1.f / 192.f);
      const float var  = fmaxf(sq * (1.f / 192.f) - mean * mean, 0.f);
      const float rstd = rsqrtf(var + 1e-5f);
      bufA[r][lane]       = __float2bfloat16((e0 - mean) * rstd * g1a + o1a);
      bufA[r][lane + 64]  = __float2bfloat16((e1 - mean) * rstd * g1b + o1b);
      bufA[r][lane + 128] = __float2bfloat16((e2 - mean) * rstd * g1c + o1c);
    }
  }
  __syncthreads();

  // ---- Phase B1: TB1 sw+ss matmuls (K=192) -> b -> bufB ----
  {
    for (int c = 0; c < 4; ++c) {
      const int ocol = wave * 64 + c * 16 + cc;
      bf16x8 Bsw[6], Bss[6];
      #pragma unroll
      for (int s = 0; s < 6; ++s) {
        Bsw[s] = *(const bf16x8*)(Wsw1 + (size_t)ocol * DIN + s * 32 + kb);
        Bss[s] = *(const bf16x8*)(Wss1 + (size_t)ocol * DIN + s * 32 + kb);
      }
      #pragma unroll
      for (int m = 0; m < 2; ++m) {
        f32x4 aSW = {0.f, 0.f, 0.f, 0.f}, aSS = {0.f, 0.f, 0.f, 0.f};
        const __hip_bfloat16* arow = &bufA[m * 16 + cc][0];
        #pragma unroll
        for (int s = 0; s < 6; ++s) {
          bf16x8 A = *(const bf16x8*)(arow + s * 32 + kb);
          aSW = mfma16(A, Bsw[s], aSW);
          aSS = mfma16(A, Bss[s], aSS);
        }
        const int rb = m * 16 + g4 * 4;
        #pragma unroll
        for (int r = 0; r < 4; ++r) {
          const float u = aSW[r];
          const float bb = (u / (1.f + __expf(-u))) * aSS[r];
          bufB[rb + r][ocol] = __float2bfloat16(bb);
        }
      }
    }
  }
  __syncthreads();

  // ---- Phase C: TB1 sig (K=192) + b@wsc (K=256), x2 -> bufX2 ----
  {
    for (int c = 0; c < 4; ++c) {
      const int ocol = wave * 64 + c * 16 + cc;
      const float bias = bsig1[ocol];
      bf16x8 Bsg[6], Bsc[8];
      #pragma unroll
      for (int s = 0; s < 6; ++s)
        Bsg[s] = *(const bf16x8*)(Wsg1 + (size_t)ocol * DIN + s * 32 + kb);
      #pragma unroll
      for (int s = 0; s < 8; ++s)
        Bsc[s] = *(const bf16x8*)(Wsc1 + (size_t)ocol * HD + s * 32 + kb);
      #pragma unroll
      for (int m = 0; m < 2; ++m) {
        f32x4 aSG = {0.f, 0.f, 0.f, 0.f}, aSC = {0.f, 0.f, 0.f, 0.f};
        const __hip_bfloat16* arow = &bufA[m * 16 + cc][0];
        const __hip_bfloat16* brow = &bufB[m * 16 + cc][0];
        #pragma unroll
        for (int s = 0; s < 6; ++s)
          aSG = mfma16(*(const bf16x8*)(arow + s * 32 + kb), Bsg[s], aSG);
        #pragma unroll
        for (int s = 0; s < 8; ++s)
          aSC = mfma16(*(const bf16x8*)(brow + s * 32 + kb), Bsc[s], aSC);
        const int rb = m * 16 + g4 * 4;
        #pragma unroll
        for (int r = 0; r < 4; ++r) {
          const float sg = 1.f / (1.f + __expf(-(aSG[r] + bias)));
          bufX2[rb + r][ocol] = __float2bfloat16(sg * aSC[r]);   // x2 (TB1 out, no residual)
        }
      }
    }
  }
  __syncthreads();

  // ---- Phase LN2: bufX2 -> xhat2 -> bufA. 8 rows per wave. ----
  {
    const float g2[4] = { ln2g[lane], ln2g[lane + 64], ln2g[lane + 128], ln2g[lane + 192] };
    const float o2[4] = { ln2b[lane], ln2b[lane + 64], ln2b[lane + 128], ln2b[lane + 192] };
    for (int rr = 0; rr < 8; ++rr) {
      const int r = wave * 8 + rr;
      float e[4];
      #pragma unroll
      for (int i = 0; i < 4; ++i) e[i] = __bfloat162float(bufX2[r][lane + 64 * i]);
      float s  = e[0] + e[1] + e[2] + e[3];
      float sq = e[0]*e[0] + e[1]*e[1] + e[2]*e[2] + e[3]*e[3];
      #pragma unroll
      for (int o = 32; o >= 1; o >>= 1) {
        s  += __shfl_xor(s,  o);
        sq += __shfl_xor(sq, o);
      }
      const float mean = s * (1.f / 256.f);
      const float var  = fmaxf(sq * (1.f / 256.f) - mean * mean, 0.f);
      const float rstd = rsqrtf(var + 1e-5f);
      #pragma unroll
      for (int i = 0; i < 4; ++i)
        bufA[r][lane + 64 * i] = __float2bfloat16(e[i] * rstd - mean * rstd) * __float2bfloat16(1.0f), // placeholder avoided below
        bufA[r][lane + 64 * i] = __float2bfloat16((e[i] - mean) * rstd * g2[i] + o2[i]);
    }
  }
  __syncthreads();

  // ---- Phase D1: TB2 sw+ss (K=256) -> b2 -> bufB ----
  {
    for (int c = 0; c < 4; ++c) {
      const int ocol = wave * 64 + c * 16 + cc;
      bf16x8 Bsw[8], Bss[8];
      #pragma unroll
      for (int s = 0; s < 8; ++s) {
        Bsw[s] = *(const bf16x8*)(Wsw2 + (size_t)ocol * HD + s * 32 + kb);
        Bss[s] = *(const bf16x8*)(Wss2 + (size_t)ocol * HD + s * 32 + kb);
      }
      #pragma unroll
      for (int m = 0; m < 2; ++m) {
        f32x4 aSW = {0.f, 0.f, 0.f, 0.f}, aSS = {0.f, 0.f, 0.f, 0.f};
        const __hip_bfloat16* arow = &bufA[m * 16 + cc][0];
        #pragma unroll
        for (int s = 0; s < 8; ++s) {
          bf16x8 A = *(const bf16x8*)(arow + s * 32 + kb);
          aSW = mfma16(A, Bsw[s], aSW);
          aSS = mfma16(A, Bss[s], aSS);
        }
        const int rb = m * 16 + g4 * 4;
        #pragma unroll
        for (int r = 0; r < 4; ++r) {
          const float u = aSW[r];
          const float bb = (u / (1.f + __expf(-u))) * aSS[r];
          bufB[rb + r][ocol] = __float2bfloat16(bb);
        }
      }
    }
  }
  __syncthreads();

  // ---- Phase D23: TB2 sig + b2@wsc2, residual, xf -> bufX2 (same slots) ----
  {
    for (int c = 0; c < 4; ++c) {
      const int ocol = wave * 64 + c * 16 + cc;
      const float bias = bsig2[ocol];
      bf16x8 Bsg[8], Bsc[8];
      #pragma unroll
      for (int s = 0; s < 8; ++s) {
        Bsg[s] = *(const bf16x8*)(Wsg2 + (size_t)ocol * HD + s * 32 + kb);
        Bsc[s] = *(const bf16x8*)(Wsc2 + (size_t)ocol * HD + s * 32 + kb);
      }
      #pragma unroll
      for (int m = 0; m < 2; ++m) {
        f32x4 aSG = {0.f, 0.f, 0.f, 0.f}, aSC = {0.f, 0.f, 0.f, 0.f};
        const __hip_bfloat16* arow = &bufA[m * 16 + cc][0];
        const __hip_bfloat16* brow = &bufB[m * 16 + cc][0];
        #pragma unroll
        for (int s = 0; s < 8; ++s) {
          aSG = mfma16(*(const bf16x8*)(arow + s * 32 + kb), Bsg[s], aSG);
          aSC = mfma16(*(const bf16x8*)(brow + s * 32 + kb), Bsc[s], aSC);
        }
        const int rb = m * 16 + g4 * 4;
        #pragma unroll
        for (int r = 0; r < 4; ++r) {
          const float sg = 1.f / (1.f + __expf(-(aSG[r] + bias)));
          const float x2v = __bfloat162float(bufX2[rb + r][ocol]);   // own slot, own lane
          bufX2[rb + r][ocol] = __float2bfloat16(x2v + sg * aSC[r]); // xf = x2 + y
        }
      }
    }
  }
  __syncthreads();

  // ---- Phase F: scores = xf @ out_w.T + out_b -> global ----
  if (t < ROWS * 4) {
    const int r = t >> 2;
    const int h = t & 3;
    const int g = row0 + r;
    if (g < N) {
      float acc = outb[h];
      const __hip_bfloat16* xp = &bufX2[r][0];
      const __hip_bfloat16* wp = Wout + h * HD;
      for (int s = 0; s < 32; ++s) {
        bf16x8 x = *(const bf16x8*)(xp + s * 8);
        bf16x8 w = *(const bf16x8*)(wp + s * 8);
        #pragma unroll
        for (int j = 0; j < 8; ++j) acc += (float)x[j] * (float)w[j];
      }
      scores[(size_t)g * 4 + h] = acc;
    }
  }
}

// ---------------------------------------------------------------------------
// Segment softmax + weighted 3-vector pooling (unchanged; <2% of runtime).
// ---------------------------------------------------------------------------
__device__ __forceinline__ int iab_lower_bound(const int* __restrict__ a, int n, int key)
{
  int lo = 0, hi = n;
  while (lo < hi) {
    const int mid = (lo + hi) >> 1;
    if (a[mid] < key) lo = mid + 1; else hi = mid;
  }
  return lo;
}

__global__ __launch_bounds__(256)
void iab_segpool_kernel(const float* __restrict__ scores,
                        const float* __restrict__ v,
                        const int* __restrict__ gidx,
                        float* __restrict__ out, int N, int E)
{
  const int seg  = blockIdx.x * 4 + (threadIdx.x >> 6);
  const int lane = threadIdx.x & 63;
  if (seg >= E) return;

  const int lo = iab_lower_bound(gidx, N, seg);
  const int hi = iab_lower_bound(gidx, N, seg + 1);

  const int h  = lane & 3;
  const int ro = lane >> 2;

  float m = -INFINITY;
  for (int base = lo; base < hi; base += 16) {
    const int r = base + ro;
    if (r < hi) m = fmaxf(m, scores[(size_t)r * 4 + h]);
  }
  #pragma unroll
  for (int o = 4; o < 64; o <<= 1) m = fmaxf(m, __shfl_xor(m, o));

  float ssum = 0.f, w0 = 0.f, w1 = 0.f, w2 = 0.f;
  for (int base = lo; base < hi; base += 16) {
    const int r = base + ro;
    if (r < hi) {
      const float e = expf(scores[(size_t)r * 4 + h] - m);
      ssum += e;
      w0 += e * v[3 * (size_t)r + 0];
      w1 += e * v[3 * (size_t)r + 1];
      w2 += e * v[3 * (size_t)r + 2];
    }
  }
  #pragma unroll
  for (int o = 4; o < 64; o <<= 1) {
    ssum += __shfl_xor(ssum, o);
    w0   += __shfl_xor(w0, o);
    w1   += __shfl_xor(w1, o);
    w2   += __shfl_xor(w2, o);
  }

  if (ro == 0) {
    const float inv = (hi > lo) ? (1.f / ssum) : 0.f;
    out[(size_t)seg * 12 + h * 3 + 0] = w0 * inv;
    out[(size_t)seg * 12 + h * 3 + 1] = w1 * inv;
    out[(size_t)seg * 12 + h * 3 + 2] = w2 * inv;
  }
}

// ---------------------------------------------------------------------------
extern "C" void kernel_launch(void* const* d_in, const int* in_sizes, int n_in,
                              void* d_out, int out_size, void* d_ws, size_t ws_size,
                              hipStream_t stream)
{
  const float* v     = (const float*)d_in[0];
  const float* af    = (const float*)d_in[1];
  const int*   gidx  = (const int*)  d_in[2];
  const float* fw    = (const float*)d_in[4];
  const float* fb    = (const float*)d_in[5];
  const float* ln1g  = (const float*)d_in[6];
  const float* ln1b  = (const float*)d_in[7];
  const float* wsw1  = (const float*)d_in[8];
  const float* wss1  = (const float*)d_in[9];
  const float* wsig1 = (const float*)d_in[10];
  const float* bsig1 = (const float*)d_in[11];
  const float* wsc1  = (const float*)d_in[12];
  const float* ln2g  = (const float*)d_in[13];
  const float* ln2b  = (const float*)d_in[14];
  const float* wsw2  = (const float*)d_in[15];
  const float* wss2  = (const float*)d_in[16];
  const float* wsig2 = (const float*)d_in[17];
  const float* bsig2 = (const float*)d_in[18];
  const float* wsc2  = (const float*)d_in[19];
  const float* outw  = (const float*)d_in[20];
  const float* outb  = (const float*)d_in[21];

  const int N = in_sizes[0] / 3;
  const int E = out_size / 12;

  float* scores = (float*)d_ws;                                   // N*4 f32 = 16 MB
  __hip_bfloat16* wc = (__hip_bfloat16*)((char*)d_ws + (size_t)N * 4 * sizeof(float));

  dim3 blk(256);
  hipLaunchKernelGGL(iab_wconv_kernel, dim3((W_TOTAL + 255) / 256), blk, 0, stream,
                     wsw1, wss1, wsig1, wsc1, wsw2, wss2, wsig2, wsc2, outw, wc);

  hipLaunchKernelGGL(iab_rows_mfma, dim3((N + ROWS - 1) / ROWS), blk, 0, stream,
                     v, af, fw, fb, ln1g, ln1b, bsig1, ln2g, ln2b, bsig2, outb,
                     wc, scores, N);

  hipLaunchKernelGGL(iab_segpool_kernel, dim3((E + 3) / 4), blk, 0, stream,
                     scores, v, gidx, (float*)d_out, N, E);
}